// Round 5
// baseline (299.144 us; speedup 1.0000x reference)
//
#include <hip/hip_runtime.h>
#include <stdint.h>

#define S_LEN 2048
#define BATCH 2
#define DM 768
#define NH 12
#define DKH 64
#define DFF 3072
#define MROWS (BATCH * S_LEN)  // 4096

typedef short bf16x8 __attribute__((ext_vector_type(8)));
typedef float f32x4 __attribute__((ext_vector_type(4)));

__device__ __forceinline__ unsigned short f2b(float f) {
    union { float f; unsigned u; } cv; cv.f = f;
    unsigned u = cv.u;
    unsigned r = (u + 0x7FFFu + ((u >> 16) & 1u)) >> 16;  // RNE
    return (unsigned short)r;
}

__device__ __forceinline__ void gload16(const void* g, void* l) {
    __builtin_amdgcn_global_load_lds(
        (const __attribute__((address_space(1))) unsigned int*)g,
        (__attribute__((address_space(3))) unsigned int*)l, 16, 0, 0);
}

// ---------------- conversion: f32 -> bf16 (vectorized) ----------------
__global__ __launch_bounds__(256) void convert_bf16_kernel(
    const float* __restrict__ in, unsigned short* __restrict__ out, int n4) {
    int i = blockIdx.x * 256 + threadIdx.x;
    if (i < n4) {
        float4 v = reinterpret_cast<const float4*>(in)[i];
        ushort4 o;
        o.x = f2b(v.x); o.y = f2b(v.y); o.z = f2b(v.z); o.w = f2b(v.w);
        reinterpret_cast<ushort4*>(out)[i] = o;
    }
}

// ---------------- transpose + convert: W[R][C] f32 -> Wt[C][R] bf16 ----------------
__global__ __launch_bounds__(256) void transpose_bf16_kernel(
    const float* __restrict__ in, unsigned short* __restrict__ out, int R, int C) {
    __shared__ float tile[32][33];
    int c0 = blockIdx.x * 32, r0 = blockIdx.y * 32;
    int tx = threadIdx.x & 31, ty = threadIdx.x >> 5;  // 32 x 8
    #pragma unroll
    for (int i = ty; i < 32; i += 8)
        tile[i][tx] = in[(size_t)(r0 + i) * C + c0 + tx];
    __syncthreads();
    #pragma unroll
    for (int i = ty; i < 32; i += 8)
        out[(size_t)(c0 + i) * R + r0 + tx] = f2b(tile[tx][i]);
}

// ============ m97-structure GEMM: 128x128 tile, BK=64, global_load_lds staging ============
#define GEMM_STAGE(kt)                                                                   \
    {                                                                                    \
        const char* ga = (const char*)(A + (size_t)bm * K + ((kt) << 6));                \
        const char* gb = (const char*)(Bt + (size_t)bn * K + ((kt) << 6));               \
        const size_t K2 = (size_t)K * 2;                                                 \
        _Pragma("unroll")                                                                \
        for (int p = 0; p < 4; ++p)                                                      \
            gload16(ga + (size_t)(srow + p * 32) * K2 + scol,                            \
                    (char*)As + p * 4096 + t * 16);                                      \
        _Pragma("unroll")                                                                \
        for (int p = 0; p < 4; ++p)                                                      \
            gload16(gb + (size_t)(srow + p * 32) * K2 + scol,                            \
                    (char*)Bs + p * 4096 + t * 16);                                      \
    }

#define GEMM_COMPUTE()                                                                   \
    _Pragma("unroll")                                                                    \
    for (int ks = 0; ks < 64; ks += 32) {                                                \
        bf16x8 af[4], bfv[4];                                                            \
        _Pragma("unroll")                                                                \
        for (int i = 0; i < 4; ++i)                                                      \
            af[i] = *reinterpret_cast<const bf16x8*>(&As[(wrow * 64 + i * 16 + lr) * 64 + ks + lk8]); \
        _Pragma("unroll")                                                                \
        for (int j = 0; j < 4; ++j)                                                      \
            bfv[j] = *reinterpret_cast<const bf16x8*>(&Bs[(wcol * 64 + j * 16 + lr) * 64 + ks + lk8]); \
        _Pragma("unroll")                                                                \
        for (int i = 0; i < 4; ++i)                                                      \
            _Pragma("unroll")                                                            \
            for (int j = 0; j < 4; ++j)                                                  \
                acc[i][j] = __builtin_amdgcn_mfma_f32_16x16x32_bf16(af[i], bfv[j], acc[i][j], 0, 0, 0); \
    }

#define GEMM_PROLOG()                                                                    \
    __shared__ __align__(16) unsigned short As[128 * 64];                                \
    __shared__ __align__(16) unsigned short Bs[128 * 64];                                \
    const int t = threadIdx.x;                                                           \
    const int wave = t >> 6, lane = t & 63;                                              \
    const int wrow = wave >> 1, wcol = wave & 1;                                         \
    const int bn = blockIdx.x * 128, bm = blockIdx.y * 128;                              \
    const int lr = lane & 15;                                                            \
    const int lk8 = (lane >> 4) << 3;                                                    \
    const int srow = t >> 3;                                                             \
    const int scol = (t & 7) * 16;                                                       \
    f32x4 acc[4][4];                                                                     \
    _Pragma("unroll")                                                                    \
    for (int i = 0; i < 4; ++i)                                                          \
        _Pragma("unroll")                                                                \
        for (int j = 0; j < 4; ++j) { f32x4 z = {0.f, 0.f, 0.f, 0.f}; acc[i][j] = z; }   \
    const int nkt = K >> 6;                                                              \
    for (int kt = 0; kt < nkt; ++kt) {                                                   \
        GEMM_STAGE(kt)                                                                   \
        __syncthreads();                                                                 \
        GEMM_COMPUTE()                                                                   \
        __syncthreads();                                                                 \
    }                                                                                    \
    const int r0 = (lane >> 4) << 2;

template <int RELU, int RES, int EF32, int EB16>
__global__ __launch_bounds__(256) void gemm128(
    const unsigned short* __restrict__ A, const unsigned short* __restrict__ Bt,
    const float* __restrict__ bias, const float* __restrict__ res,
    float* __restrict__ outf, unsigned short* __restrict__ outb,
    int M, int N, int K) {
    GEMM_PROLOG()
    #pragma unroll
    for (int i = 0; i < 4; ++i) {
        const int row_b = bm + wrow * 64 + i * 16 + r0;
        #pragma unroll
        for (int j = 0; j < 4; ++j) {
            const int col = bn + wcol * 64 + j * 16 + lr;
            const float bvv = bias[col];
            #pragma unroll
            for (int r = 0; r < 4; ++r) {
                float vv = acc[i][j][r] + bvv;
                if (RES) vv += res[(size_t)(row_b + r) * N + col];
                if (RELU) vv = vv > 0.f ? vv : 0.f;
                if (EF32) outf[(size_t)(row_b + r) * N + col] = vv;
                if (EB16) outb[(size_t)(row_b + r) * N + col] = f2b(vv);
            }
        }
    }
}

// ============ BM=128 x BN=64 variant for N=768 GEMMs (grid fill) ============
template <int RELU, int RES, int EF32, int EB16>
__global__ __launch_bounds__(256) void gemm_bt64(
    const unsigned short* __restrict__ A, const unsigned short* __restrict__ Bt,
    const float* __restrict__ bias, const float* __restrict__ res,
    float* __restrict__ outf, unsigned short* __restrict__ outb,
    int M, int N, int K) {
    __shared__ __align__(16) unsigned short As[128 * 64];
    __shared__ __align__(16) unsigned short Bs[64 * 64];
    const int t = threadIdx.x;
    const int wave = t >> 6, lane = t & 63;
    const int bn = blockIdx.x * 64, bm = blockIdx.y * 128;
    const int lr = lane & 15;
    const int lk8 = (lane >> 4) << 3;
    const int srow = t >> 3;
    const int scol = (t & 7) * 16;
    f32x4 acc[2][4];
    #pragma unroll
    for (int i = 0; i < 2; ++i)
        #pragma unroll
        for (int j = 0; j < 4; ++j) { f32x4 z = {0.f, 0.f, 0.f, 0.f}; acc[i][j] = z; }
    const int nkt = K >> 6;
    for (int kt = 0; kt < nkt; ++kt) {
        const char* ga = (const char*)(A + (size_t)bm * K + (kt << 6));
        const char* gb = (const char*)(Bt + (size_t)bn * K + (kt << 6));
        const size_t K2 = (size_t)K * 2;
        #pragma unroll
        for (int p = 0; p < 4; ++p)
            gload16(ga + (size_t)(srow + p * 32) * K2 + scol, (char*)As + p * 4096 + t * 16);
        #pragma unroll
        for (int p = 0; p < 2; ++p)
            gload16(gb + (size_t)(srow + p * 32) * K2 + scol, (char*)Bs + p * 4096 + t * 16);
        __syncthreads();
        #pragma unroll
        for (int ks = 0; ks < 64; ks += 32) {
            bf16x8 af[2], bfv[4];
            #pragma unroll
            for (int i = 0; i < 2; ++i)
                af[i] = *reinterpret_cast<const bf16x8*>(&As[(wave * 32 + i * 16 + lr) * 64 + ks + lk8]);
            #pragma unroll
            for (int j = 0; j < 4; ++j)
                bfv[j] = *reinterpret_cast<const bf16x8*>(&Bs[(j * 16 + lr) * 64 + ks + lk8]);
            #pragma unroll
            for (int i = 0; i < 2; ++i)
                #pragma unroll
                for (int j = 0; j < 4; ++j)
                    acc[i][j] = __builtin_amdgcn_mfma_f32_16x16x32_bf16(af[i], bfv[j], acc[i][j], 0, 0, 0);
        }
        __syncthreads();
    }
    const int r0 = (lane >> 4) << 2;
    #pragma unroll
    for (int i = 0; i < 2; ++i) {
        const int row_b = bm + wave * 32 + i * 16 + r0;
        #pragma unroll
        for (int j = 0; j < 4; ++j) {
            const int col = bn + j * 16 + lr;
            const float bvv = bias[col];
            #pragma unroll
            for (int r = 0; r < 4; ++r) {
                float vv = acc[i][j][r] + bvv;
                if (RES) vv += res[(size_t)(row_b + r) * N + col];
                if (RELU) vv = vv > 0.f ? vv : 0.f;
                if (EF32) outf[(size_t)(row_b + r) * N + col] = vv;
                if (EB16) outb[(size_t)(row_b + r) * N + col] = f2b(vv);
            }
        }
    }
}

// fused QKV epilogue: N=2304 = [Q | K | V]; Q scaled, K plain -> [B,H,S,64]; V -> [B,H,64,S]
__global__ __launch_bounds__(256) void gemm128_qkv(
    const unsigned short* __restrict__ A, const unsigned short* __restrict__ Bt,
    const float* __restrict__ bq, const float* __restrict__ bk, const float* __restrict__ bv,
    unsigned short* __restrict__ q16, unsigned short* __restrict__ k16,
    unsigned short* __restrict__ vt16, int M, int N, int K, float qscale) {
    GEMM_PROLOG()
    #pragma unroll
    for (int i = 0; i < 4; ++i) {
        const int row_b = bm + wrow * 64 + i * 16 + r0;
        const int b = row_b >> 11, s = row_b & 2047;
        #pragma unroll
        for (int j = 0; j < 4; ++j) {
            const int col = bn + wcol * 64 + j * 16 + lr;
            const int sec = (col >= 2 * DM) ? 2 : (col >= DM ? 1 : 0);
            const int nc = col - sec * DM;
            const int h = nc >> 6, d = nc & 63;
            const float bvv = (sec == 0 ? bq : (sec == 1 ? bk : bv))[nc];
            if (sec == 2) {
                ushort4 w;
                w.x = f2b(acc[i][j][0] + bvv);
                w.y = f2b(acc[i][j][1] + bvv);
                w.z = f2b(acc[i][j][2] + bvv);
                w.w = f2b(acc[i][j][3] + bvv);
                *reinterpret_cast<ushort4*>(
                    vt16 + (((size_t)(b * NH + h) * DKH) + d) * S_LEN + s) = w;
            } else {
                const float sc = (sec == 0) ? qscale : 1.f;
                unsigned short* dst = (sec == 0) ? q16 : k16;
                #pragma unroll
                for (int r = 0; r < 4; ++r)
                    dst[(((size_t)(b * NH + h) * S_LEN) + s + r) * DKH + d] =
                        f2b((acc[i][j][r] + bvv) * sc);
            }
        }
    }
}

// ---------------- MFMA causal flash attention: wave-independent, no barriers ----------------
// Grid: x = head (L2 locality: 3 heads/XCD), y = q-block (reversed -> heavy first).
// Each wave owns 32 q-rows (2 groups of 16). K/V read DIRECTLY from global (L2-resident,
// m169 lesson: don't stage what cache-fits). Only per-wave Pl LDS for the P relayout.
__global__ __launch_bounds__(256) void attn_mfma_kernel(
    const unsigned short* __restrict__ q16,   // [B,H,S,64]
    const unsigned short* __restrict__ k16,   // [B,H,S,64]
    const unsigned short* __restrict__ vt16,  // [B,H,64,S]
    unsigned short* __restrict__ ctx16) {     // [B,S,DM]
    __shared__ __align__(16) unsigned short Pl[8][16][72];  // [wave*2+g][q=lr][key]
    const int t = threadIdx.x, wave = t >> 6, lane = t & 63;
    const int bh = blockIdx.x;
    const int qb = (gridDim.y - 1) - blockIdx.y;  // heavy blocks dispatched first
    const int b = bh / NH, h = bh % NH;
    const size_t hbase = (size_t)bh * S_LEN * DKH;
    const int lr = lane & 15;
    const int g4 = (lane >> 4) << 2;
    const int lk8 = (lane >> 4) << 3;
    const int sW = (qb << 7) + wave * 32;  // this wave's first q row

    // Q fragments in registers (pre-scaled to exp2 domain by the QKV GEMM)
    bf16x8 qa[2][2];
    #pragma unroll
    for (int g = 0; g < 2; ++g)
        #pragma unroll
        for (int ks = 0; ks < 2; ++ks)
            qa[g][ks] = *reinterpret_cast<const bf16x8*>(
                q16 + hbase + (size_t)(sW + g * 16 + lr) * DKH + ks * 32 + lk8);

    float mst[2] = {-3e38f, -3e38f}, lst[2] = {0.f, 0.f};
    f32x4 acc[2][4];
    #pragma unroll
    for (int g = 0; g < 2; ++g)
        #pragma unroll
        for (int j = 0; j < 4; ++j) { f32x4 z = {0.f, 0.f, 0.f, 0.f}; acc[g][j] = z; }

    const unsigned short* kb = k16 + hbase;
    const unsigned short* vbg = vt16 + hbase;
    const int nt = (sW >> 6) + 1;
    for (int kt = 0; kt < nt; ++kt) {
        const int k0 = kt << 6;

        // S^T = K * Q^T  (K fragments straight from global/L2)
        f32x4 sc[2][4];
        #pragma unroll
        for (int g = 0; g < 2; ++g)
            #pragma unroll
            for (int j = 0; j < 4; ++j) { f32x4 z = {0.f, 0.f, 0.f, 0.f}; sc[g][j] = z; }
        __builtin_amdgcn_s_setprio(1);
        #pragma unroll
        for (int ks = 0; ks < 2; ++ks) {
            #pragma unroll
            for (int j = 0; j < 4; ++j) {
                bf16x8 ka = *reinterpret_cast<const bf16x8*>(
                    kb + (size_t)(k0 + j * 16 + lr) * DKH + ks * 32 + lk8);
                #pragma unroll
                for (int g = 0; g < 2; ++g)
                    sc[g][j] = __builtin_amdgcn_mfma_f32_16x16x32_bf16(ka, qa[g][ks], sc[g][j], 0, 0, 0);
            }
        }
        __builtin_amdgcn_s_setprio(0);

        // online softmax (exp2 domain); only the last tile crosses the diagonal
        const bool lastt = (kt == nt - 1);
        #pragma unroll
        for (int g = 0; g < 2; ++g) {
            const int qg = sW + g * 16 + lr;
            if (lastt) {
                #pragma unroll
                for (int j = 0; j < 4; ++j)
                    #pragma unroll
                    for (int r = 0; r < 4; ++r)
                        if (k0 + j * 16 + g4 + r > qg) sc[g][j][r] = -3e38f;
            }
            float m01 = fmaxf(fmaxf(sc[g][0][0], sc[g][0][1]), fmaxf(sc[g][0][2], sc[g][0][3]));
            float m11 = fmaxf(fmaxf(sc[g][1][0], sc[g][1][1]), fmaxf(sc[g][1][2], sc[g][1][3]));
            float m21 = fmaxf(fmaxf(sc[g][2][0], sc[g][2][1]), fmaxf(sc[g][2][2], sc[g][2][3]));
            float m31 = fmaxf(fmaxf(sc[g][3][0], sc[g][3][1]), fmaxf(sc[g][3][2], sc[g][3][3]));
            float tm = fmaxf(fmaxf(m01, m11), fmaxf(m21, m31));
            tm = fmaxf(tm, __shfl_xor(tm, 16));
            tm = fmaxf(tm, __shfl_xor(tm, 32));
            const float mn = fmaxf(mst[g], tm);
            const float corr = exp2f(mst[g] - mn);
            float ts = 0.f;
            #pragma unroll
            for (int j = 0; j < 4; ++j)
                #pragma unroll
                for (int r = 0; r < 4; ++r) {
                    const float p = exp2f(sc[g][j][r] - mn);
                    sc[g][j][r] = p;
                    ts += p;
                }
            ts += __shfl_xor(ts, 16);
            ts += __shfl_xor(ts, 32);
            lst[g] = lst[g] * corr + ts;
            mst[g] = mn;
            #pragma unroll
            for (int r = 0; r < 4; ++r) {
                const float cr = __shfl(corr, g4 + r);
                #pragma unroll
                for (int j = 0; j < 4; ++j) acc[g][j][r] *= cr;
            }
            #pragma unroll
            for (int j = 0; j < 4; ++j) {
                ushort4 w;
                w.x = f2b(sc[g][j][0]); w.y = f2b(sc[g][j][1]);
                w.z = f2b(sc[g][j][2]); w.w = f2b(sc[g][j][3]);
                *reinterpret_cast<ushort4*>(&Pl[wave * 2 + g][lr][j * 16 + g4]) = w;
            }
        }

        // PV: out[q][d] += P[q][key] * Vt[d][key]^T  (V fragments from global/L2)
        __builtin_amdgcn_s_setprio(1);
        #pragma unroll
        for (int kc = 0; kc < 64; kc += 32) {
            bf16x8 pa[2];
            #pragma unroll
            for (int g = 0; g < 2; ++g)
                pa[g] = *reinterpret_cast<const bf16x8*>(&Pl[wave * 2 + g][lr][kc + lk8]);
            #pragma unroll
            for (int j = 0; j < 4; ++j) {
                bf16x8 vb = *reinterpret_cast<const bf16x8*>(
                    vbg + (size_t)(j * 16 + lr) * S_LEN + k0 + kc + lk8);
                #pragma unroll
                for (int g = 0; g < 2; ++g)
                    acc[g][j] = __builtin_amdgcn_mfma_f32_16x16x32_bf16(pa[g], vb, acc[g][j], 0, 0, 0);
            }
        }
        __builtin_amdgcn_s_setprio(0);
    }

    #pragma unroll
    for (int g = 0; g < 2; ++g) {
        const float li = 1.f / lst[g];
        #pragma unroll
        for (int r = 0; r < 4; ++r) {
            const float lrc = __shfl(li, g4 + r);
            const int srow = sW + g * 16 + g4 + r;
            #pragma unroll
            for (int j = 0; j < 4; ++j) {
                ctx16[((size_t)b * S_LEN + srow) * DM + h * DKH + j * 16 + lr] =
                    f2b(acc[g][j][r] * lrc);
            }
        }
    }
}

// ---------------- row LayerNorm, optional bf16 copy ----------------
template <int EB16>
__global__ __launch_bounds__(256) void layernorm_kernel(
    const float* __restrict__ in, const float* __restrict__ gam, const float* __restrict__ bet,
    float* __restrict__ outf, unsigned short* __restrict__ outb) {
    __shared__ float red[8];
    const int row = blockIdx.x, t = threadIdx.x;
    const int wave = t >> 6, lane = t & 63;
    const float* p = in + (size_t)row * DM;
    const float v0 = p[t], v1 = p[t + 256], v2 = p[t + 512];
    float s = v0 + v1 + v2;
    float sq = v0 * v0 + v1 * v1 + v2 * v2;
    #pragma unroll
    for (int off = 32; off > 0; off >>= 1) { s += __shfl_xor(s, off); sq += __shfl_xor(sq, off); }
    if (lane == 0) { red[wave] = s; red[wave + 4] = sq; }
    __syncthreads();
    s = red[0] + red[1] + red[2] + red[3];
    sq = red[4] + red[5] + red[6] + red[7];
    const float mu = s * (1.f / DM);
    const float var = sq * (1.f / DM) - mu * mu;
    const float rs = rsqrtf(var + 1e-5f);
    #pragma unroll
    for (int i = 0; i < 3; ++i) {
        const int c = t + i * 256;
        const float vv = (i == 0 ? v0 : (i == 1 ? v1 : v2));
        const float y = (vv - mu) * rs * gam[c] + bet[c];
        outf[(size_t)row * DM + c] = y;
        if (EB16) outb[(size_t)row * DM + c] = f2b(y);
    }
}

extern "C" void kernel_launch(void* const* d_in, const int* in_sizes, int n_in,
                              void* d_out, int out_size, void* d_ws, size_t ws_size,
                              hipStream_t stream) {
    const float* x   = (const float*)d_in[0];
    const float* wq  = (const float*)d_in[1];
    const float* bq  = (const float*)d_in[2];
    const float* wk  = (const float*)d_in[3];
    const float* bk  = (const float*)d_in[4];
    const float* wv  = (const float*)d_in[5];
    const float* bv  = (const float*)d_in[6];
    const float* wo  = (const float*)d_in[7];
    const float* bo  = (const float*)d_in[8];
    const float* w1  = (const float*)d_in[9];
    const float* b1  = (const float*)d_in[10];
    const float* w2  = (const float*)d_in[11];
    const float* b2  = (const float*)d_in[12];
    const float* g1  = (const float*)d_in[13];
    const float* be1 = (const float*)d_in[14];
    const float* g2  = (const float*)d_in[15];
    const float* be2 = (const float*)d_in[16];

    char* wp = (char*)d_ws;
    auto alloc = [&](size_t bytes) -> void* {
        void* r = (void*)wp;
        wp += (bytes + 255) & ~(size_t)255;
        return r;
    };
    const int M = MROWS;
    unsigned short* wqkv16 = (unsigned short*)alloc((size_t)3 * DM * DM * 2);  // [2304][768]
    unsigned short* wo16 = (unsigned short*)alloc((size_t)DM * DM * 2);
    unsigned short* w116 = (unsigned short*)alloc((size_t)DM * DFF * 2);
    unsigned short* w216 = (unsigned short*)alloc((size_t)DM * DFF * 2);
    unsigned short* ctx16 = (unsigned short*)alloc((size_t)M * DM * 2);
    float* y1 = (float*)alloc((size_t)M * DM * 4);
    unsigned short* x16  = (unsigned short*)alloc((size_t)M * DM * 2);
    unsigned short* q16  = (unsigned short*)alloc((size_t)M * DM * 2);
    unsigned short* k16  = (unsigned short*)alloc((size_t)M * DM * 2);
    unsigned short* vt16 = (unsigned short*)alloc((size_t)M * DM * 2);
    unsigned short* ff116 = x16;    // [M,DFF] bf16 over x16..vt16 (contiguous, dead after QKV/attn)
    unsigned short* x116  = ctx16;  // LN1 bf16 output

    convert_bf16_kernel<<<(M * DM / 4 + 255) / 256, 256, 0, stream>>>(x, x16, M * DM / 4);
    transpose_bf16_kernel<<<dim3(DM / 32, DM / 32), 256, 0, stream>>>(wq, wqkv16, DM, DM);
    transpose_bf16_kernel<<<dim3(DM / 32, DM / 32), 256, 0, stream>>>(wk, wqkv16 + (size_t)DM * DM, DM, DM);
    transpose_bf16_kernel<<<dim3(DM / 32, DM / 32), 256, 0, stream>>>(wv, wqkv16 + (size_t)2 * DM * DM, DM, DM);
    transpose_bf16_kernel<<<dim3(DM / 32, DM / 32), 256, 0, stream>>>(wo, wo16, DM, DM);
    transpose_bf16_kernel<<<dim3(DFF / 32, DM / 32), 256, 0, stream>>>(w1, w116, DM, DFF);
    transpose_bf16_kernel<<<dim3(DM / 32, DFF / 32), 256, 0, stream>>>(w2, w216, DFF, DM);

    const float QSCALE = 0.125f * 1.44269504088896f;
    gemm128_qkv<<<dim3(3 * DM / 128, M / 128), 256, 0, stream>>>(
        x16, wqkv16, bq, bk, bv, q16, k16, vt16, M, 3 * DM, DM, QSCALE);

    attn_mfma_kernel<<<dim3(BATCH * NH, S_LEN / 128), 256, 0, stream>>>(q16, k16, vt16, ctx16);

    gemm_bt64<0, 1, 1, 0><<<dim3(DM / 64, M / 128), 256, 0, stream>>>(
        ctx16, wo16, bo, x, y1, nullptr, M, DM, DM);
    layernorm_kernel<1><<<M, 256, 0, stream>>>(y1, g1, be1, y1, x116);

    gemm128<1, 0, 0, 1><<<dim3(DFF / 128, M / 128), 256, 0, stream>>>(
        x116, w116, b1, nullptr, nullptr, ff116, M, DFF, DM);
    gemm_bt64<0, 1, 1, 0><<<dim3(DM / 64, M / 128), 256, 0, stream>>>(
        ff116, w216, b2, y1, (float*)d_out, nullptr, M, DM, DFF);
    layernorm_kernel<0><<<M, 256, 0, stream>>>((float*)d_out, g2, be2, (float*)d_out, nullptr);
}